// Round 1
// 453.828 us; speedup vs baseline: 2.4746x; 2.4746x over previous
//
#include <hip/hip_runtime.h>

// Problem constants
#define BATCH 2
#define SEQ   2048
#define EMB   1024
#define NH    16
#define HD    64

typedef __attribute__((ext_vector_type(8))) short short8;
typedef __attribute__((ext_vector_type(4))) float floatx4;
typedef __attribute__((ext_vector_type(4))) unsigned short ushort4_t;
typedef unsigned short u16;

// fp32 -> bf16 (RNE) as raw ushort bits
__device__ __forceinline__ u16 f32_to_bf16(float f) {
    union { float f; unsigned int u; } v; v.f = f;
    unsigned int r = v.u + 0x7fffu + ((v.u >> 16) & 1u);
    return (u16)(r >> 16);
}
__device__ __forceinline__ float bf16_to_f32(u16 h) {
    union { unsigned int u; float f; } v; v.u = (unsigned int)h << 16;
    return v.f;
}

// ---------------------------------------------------------------------------
// Prep 1: split fp32 array into bf16 hi + bf16 lo (x = hi + lo to ~16 bits)
// ---------------------------------------------------------------------------
__global__ __launch_bounds__(256)
void split_bf16(const float* __restrict__ in, u16* __restrict__ hi,
                u16* __restrict__ lo, int n4) {
    int i = blockIdx.x * 256 + threadIdx.x;
    if (i >= n4) return;
    float4 v = ((const float4*)in)[i];
    float vf[4] = {v.x, v.y, v.z, v.w};
    ushort4_t hv, lv;
#pragma unroll
    for (int j = 0; j < 4; ++j) {
        u16 hb = f32_to_bf16(vf[j]);
        hv[j] = hb;
        lv[j] = f32_to_bf16(vf[j] - bf16_to_f32(hb));
    }
    ((ushort4_t*)hi)[i] = hv;
    ((ushort4_t*)lo)[i] = lv;
}

// ---------------------------------------------------------------------------
// Prep 2: W [K][N] fp32 -> Wt [N][K] bf16 hi (+ optional lo). 32x32 LDS tile.
// ---------------------------------------------------------------------------
__global__ __launch_bounds__(256)
void transpose_split_bf16(const float* __restrict__ W, u16* __restrict__ hi,
                          u16* __restrict__ lo, int K, int N, int do_lo) {
    __shared__ float t[32][33];
    const int n0 = blockIdx.x * 32, k0 = blockIdx.y * 32;
    const int r = threadIdx.x >> 3, c4 = (threadIdx.x & 7) * 4;
    float4 v = *(const float4*)&W[(size_t)(k0 + r) * N + n0 + c4];
    t[r][c4 + 0] = v.x; t[r][c4 + 1] = v.y;
    t[r][c4 + 2] = v.z; t[r][c4 + 3] = v.w;
    __syncthreads();
    ushort4_t hv, lv;
#pragma unroll
    for (int j = 0; j < 4; ++j) {
        float x = t[c4 + j][r];          // = W[k0+c4+j][n0+r]
        u16 hb = f32_to_bf16(x);
        hv[j] = hb;
        lv[j] = f32_to_bf16(x - bf16_to_f32(hb));
    }
    *(ushort4_t*)&hi[(size_t)(n0 + r) * K + k0 + c4] = hv;
    if (do_lo) *(ushort4_t*)&lo[(size_t)(n0 + r) * K + k0 + c4] = lv;
}

// ---------------------------------------------------------------------------
// GEMM1 (MFMA, split-precision): qkv = x @ Wqkv + bqkv at ~fp32 accuracy via
// xh*wh + xh*wl + xl*wh (3 MFMAs). 128x128 tile, BK=32, 4 waves, 64x64/wave.
// A = x [M][K] bf16 hi/lo; B = Wqkv^T [N][K] bf16 hi/lo (both k-contiguous).
// Epilogue scatters bf16 into head-split Q/K/V [(b*NH+h)*SEQ + s][HD].
// mfma_f32_16x16x32_bf16 layouts (m89-verified):
//   A[m=lane&15][k=quad*8+j]  B[k=quad*8+j][n=lane&15]  D: col=lane&15,
//   row=quad*4+reg.
// ---------------------------------------------------------------------------
#define ALD 40   // LDS row stride in ushorts (80 B): 2-way bank alias = free

__global__ __launch_bounds__(256)
void gemm_qkv_mfma(const u16* __restrict__ Xh, const u16* __restrict__ Xl,
                   const u16* __restrict__ Wh, const u16* __restrict__ Wl,
                   const float* __restrict__ bias,
                   u16* __restrict__ Qh, u16* __restrict__ Kh,
                   u16* __restrict__ Vh) {
    const int K = EMB;   // 1024
    __shared__ u16 Ah[128 * ALD];
    __shared__ u16 Al[128 * ALD];
    __shared__ u16 Bh[128 * ALD];
    __shared__ u16 Bl[128 * ALD];

    const int tid  = threadIdx.x;
    const int wave = tid >> 6, lane = tid & 63;
    const int quad = lane >> 4, lp = lane & 15;

    // XCD-aware swizzle: 24x32 = 768 blocks, 768 % 8 == 0 (bijective).
    const int linear = blockIdx.y * 24 + blockIdx.x;
    const int swz = (linear & 7) * 96 + (linear >> 3);
    const int bx = swz % 24, by = swz / 24;
    const int row0 = by * 128, col0 = bx * 128;
    const int wm = (wave >> 1) * 64, wn = (wave & 1) * 64;

    const int srow = tid >> 2, sseg = (tid & 3) * 8;   // staging map

    floatx4 acc[4][4];
#pragma unroll
    for (int i = 0; i < 4; ++i)
#pragma unroll
        for (int j = 0; j < 4; ++j) acc[i][j] = (floatx4){0.f, 0.f, 0.f, 0.f};

    for (int k0 = 0; k0 < K; k0 += 32) {
        // stage 128x32 bf16 of each of the 4 operands
#pragma unroll
        for (int it = 0; it < 2; ++it) {
            int r = srow + it * 64;
            size_t ga = (size_t)(row0 + r) * K + k0 + sseg;
            *(uint4*)&Ah[r * ALD + sseg] = *(const uint4*)&Xh[ga];
            *(uint4*)&Al[r * ALD + sseg] = *(const uint4*)&Xl[ga];
            size_t gb = (size_t)(col0 + r) * K + k0 + sseg;
            *(uint4*)&Bh[r * ALD + sseg] = *(const uint4*)&Wh[gb];
            *(uint4*)&Bl[r * ALD + sseg] = *(const uint4*)&Wl[gb];
        }
        __syncthreads();

        short8 ah[4], al[4];
#pragma unroll
        for (int mi = 0; mi < 4; ++mi) {
            ah[mi] = *(const short8*)&Ah[(wm + mi * 16 + lp) * ALD + quad * 8];
            al[mi] = *(const short8*)&Al[(wm + mi * 16 + lp) * ALD + quad * 8];
        }
#pragma unroll
        for (int ni = 0; ni < 4; ++ni) {
            short8 bh = *(const short8*)&Bh[(wn + ni * 16 + lp) * ALD + quad * 8];
            short8 bl = *(const short8*)&Bl[(wn + ni * 16 + lp) * ALD + quad * 8];
#pragma unroll
            for (int mi = 0; mi < 4; ++mi) {
                acc[mi][ni] = __builtin_amdgcn_mfma_f32_16x16x32_bf16(ah[mi], bh, acc[mi][ni], 0, 0, 0);
                acc[mi][ni] = __builtin_amdgcn_mfma_f32_16x16x32_bf16(ah[mi], bl, acc[mi][ni], 0, 0, 0);
                acc[mi][ni] = __builtin_amdgcn_mfma_f32_16x16x32_bf16(al[mi], bh, acc[mi][ni], 0, 0, 0);
            }
        }
        __syncthreads();
    }

    // epilogue: scatter bf16 into head-split Q/K/V
#pragma unroll
    for (int ni = 0; ni < 4; ++ni) {
        const int c = col0 + wn + ni * 16 + lp;    // 0..3071
        const int h = c / 192;
        const int rem = c - h * 192;
        const int which = rem >> 6;                // 0=q 1=k 2=v
        const int d = rem & 63;
        u16* __restrict__ P = (which == 0) ? Qh : (which == 1) ? Kh : Vh;
        const float bb = bias[c];
#pragma unroll
        for (int mi = 0; mi < 4; ++mi) {
            floatx4 a = acc[mi][ni];
#pragma unroll
            for (int r = 0; r < 4; ++r) {
                int m = row0 + wm + mi * 16 + quad * 4 + r;   // b*SEQ + s
                int b = m >> 11, s = m & (SEQ - 1);
                P[((size_t)(b * NH + h) * SEQ + s) * HD + d] =
                    f32_to_bf16(a[r] + bb);
            }
        }
    }
}

// ---------------------------------------------------------------------------
// GEMM3 (MFMA bf16): out = ctx @ Wout + bout, fp32 out.
// A = ctx [M][K] bf16; B = Wout^T [N][K] bf16. Same structure, 1 MFMA.
// ---------------------------------------------------------------------------
__global__ __launch_bounds__(256)
void gemm_out_mfma(const u16* __restrict__ Ch, const u16* __restrict__ Oh,
                   const float* __restrict__ bias, float* __restrict__ out) {
    const int K = EMB, N = EMB;
    __shared__ u16 Ah[128 * ALD];
    __shared__ u16 Bh[128 * ALD];

    const int tid  = threadIdx.x;
    const int wave = tid >> 6, lane = tid & 63;
    const int quad = lane >> 4, lp = lane & 15;

    // XCD swizzle: 8x32 = 256 blocks, 256 % 8 == 0.
    const int linear = blockIdx.y * 8 + blockIdx.x;
    const int swz = (linear & 7) * 32 + (linear >> 3);
    const int bx = swz & 7, by = swz >> 3;
    const int row0 = by * 128, col0 = bx * 128;
    const int wm = (wave >> 1) * 64, wn = (wave & 1) * 64;

    const int srow = tid >> 2, sseg = (tid & 3) * 8;

    floatx4 acc[4][4];
#pragma unroll
    for (int i = 0; i < 4; ++i)
#pragma unroll
        for (int j = 0; j < 4; ++j) acc[i][j] = (floatx4){0.f, 0.f, 0.f, 0.f};

    for (int k0 = 0; k0 < K; k0 += 32) {
#pragma unroll
        for (int it = 0; it < 2; ++it) {
            int r = srow + it * 64;
            *(uint4*)&Ah[r * ALD + sseg] =
                *(const uint4*)&Ch[(size_t)(row0 + r) * K + k0 + sseg];
            *(uint4*)&Bh[r * ALD + sseg] =
                *(const uint4*)&Oh[(size_t)(col0 + r) * K + k0 + sseg];
        }
        __syncthreads();

        short8 ah[4];
#pragma unroll
        for (int mi = 0; mi < 4; ++mi)
            ah[mi] = *(const short8*)&Ah[(wm + mi * 16 + lp) * ALD + quad * 8];
#pragma unroll
        for (int ni = 0; ni < 4; ++ni) {
            short8 bh = *(const short8*)&Bh[(wn + ni * 16 + lp) * ALD + quad * 8];
#pragma unroll
            for (int mi = 0; mi < 4; ++mi)
                acc[mi][ni] = __builtin_amdgcn_mfma_f32_16x16x32_bf16(ah[mi], bh, acc[mi][ni], 0, 0, 0);
        }
        __syncthreads();
    }

#pragma unroll
    for (int ni = 0; ni < 4; ++ni) {
        const int c = col0 + wn + ni * 16 + lp;
        const float bb = bias[c];
#pragma unroll
        for (int mi = 0; mi < 4; ++mi) {
            floatx4 a = acc[mi][ni];
#pragma unroll
            for (int r = 0; r < 4; ++r) {
                int m = row0 + wm + mi * 16 + quad * 4 + r;
                out[(size_t)m * N + c] = a[r] + bb;
            }
        }
    }
}

// ---------------------------------------------------------------------------
// MFMA flash-style attention, two passes (stats, then recompute+write+PV).
// Block: 256 thr = 4 waves. Block handles 64 query rows of one (b,h).
// Wave w owns query rows [16w, 16w+16). ctx now written as bf16.
// ---------------------------------------------------------------------------
#define QT 64
#define KT 64
#define LDST 72   // LDS row stride in ushorts: 144 B (16B-aligned, bank-spread)

__global__ __launch_bounds__(256)
void attn_mfma(const u16* __restrict__ Qh,
               const u16* __restrict__ Kh,
               const u16* __restrict__ Vh,
               float* __restrict__ attn,   // [B,H,S,S]
               u16* __restrict__ ctx) {    // [B,S,EMB] bf16
    __shared__ u16 qs[QT * LDST];
    __shared__ u16 ks[KT * LDST];
    __shared__ u16 vt[HD * LDST];
    __shared__ u16 ps[4 * 16 * LDST];

    const int tid  = threadIdx.x;
    const int wave = tid >> 6, lane = tid & 63;
    const int quad = lane >> 4, lp = lane & 15;
    const int q0 = blockIdx.x * QT;
    const int bh = blockIdx.y;                 // b*NH + h
    const int h  = bh & (NH - 1);
    const float slope = exp2f(-0.5f * (float)(h + 1));

    const u16* Qbase = Qh + ((size_t)bh * SEQ + q0) * HD;
    const u16* Kbase = Kh + (size_t)bh * SEQ * HD;
    const u16* Vbase = Vh + (size_t)bh * SEQ * HD;

    // ---- stage Q tile (64 x 64 bf16), row-major, stride LDST ----
    for (int c = tid; c < QT * HD / 8; c += 256) {   // 512 chunks of 8 bf16
        int row = c >> 3, seg = c & 7;
        *(uint4*)&qs[row * LDST + seg * 8] =
            *(const uint4*)&Qbase[(size_t)row * HD + seg * 8];
    }
    __syncthreads();

    // Q A-fragments are loop-invariant: hoist.
    const short8 qa0 = *(const short8*)&qs[(16 * wave + lp) * LDST + quad * 8];
    const short8 qa1 = *(const short8*)&qs[(16 * wave + lp) * LDST + 32 + quad * 8];

    const int ig = q0 + 16 * wave + quad * 4;   // +r = global query row

    float m[4], l[4];
#pragma unroll
    for (int r = 0; r < 4; ++r) { m[r] = -1e30f; l[r] = 0.f; }

    // ================= pass 1: online max/sum =================
    for (int kt = 0; kt < SEQ / KT; ++kt) {
        __syncthreads();
        const u16* Ksrc = Kbase + (size_t)kt * KT * HD;
        for (int c = tid; c < KT * HD / 8; c += 256) {
            int row = c >> 3, seg = c & 7;
            *(uint4*)&ks[row * LDST + seg * 8] =
                *(const uint4*)&Ksrc[(size_t)row * HD + seg * 8];
        }
        __syncthreads();

        float sv[4][4];
        float tmax[4] = {-1e30f, -1e30f, -1e30f, -1e30f};
#pragma unroll
        for (int t = 0; t < 4; ++t) {
            short8 b0 = *(const short8*)&ks[(16 * t + lp) * LDST + quad * 8];
            short8 b1 = *(const short8*)&ks[(16 * t + lp) * LDST + 32 + quad * 8];
            floatx4 c = {0.f, 0.f, 0.f, 0.f};
            c = __builtin_amdgcn_mfma_f32_16x16x32_bf16(qa0, b0, c, 0, 0, 0);
            c = __builtin_amdgcn_mfma_f32_16x16x32_bf16(qa1, b1, c, 0, 0, 0);
            int jg = kt * KT + 16 * t + lp;
#pragma unroll
            for (int r = 0; r < 4; ++r) {
                float s = c[r] * 0.125f + slope * (float)(jg - (ig + r));
                sv[t][r] = s;
                tmax[r] = fmaxf(tmax[r], s);
            }
        }
#pragma unroll
        for (int r = 0; r < 4; ++r) {
#pragma unroll
            for (int off = 1; off < 16; off <<= 1)
                tmax[r] = fmaxf(tmax[r], __shfl_xor(tmax[r], off));
            float mn = fmaxf(m[r], tmax[r]);
            float alpha = __expf(m[r] - mn);
            float psum = 0.f;
#pragma unroll
            for (int t = 0; t < 4; ++t) psum += __expf(sv[t][r] - mn);
#pragma unroll
            for (int off = 1; off < 16; off <<= 1)
                psum += __shfl_xor(psum, off);
            l[r] = l[r] * alpha + psum;
            m[r] = mn;
        }
    }

    float invl[4];
#pragma unroll
    for (int r = 0; r < 4; ++r) invl[r] = 1.0f / l[r];

    // ================= pass 2: recompute, write attn, PV =================
    floatx4 o[4];
#pragma unroll
    for (int t = 0; t < 4; ++t) o[t] = (floatx4){0.f, 0.f, 0.f, 0.f};

    float* arow = attn + (size_t)bh * SEQ * SEQ;

    for (int kt = 0; kt < SEQ / KT; ++kt) {
        __syncthreads();
        const u16* Ksrc = Kbase + (size_t)kt * KT * HD;
        const u16* Vsrc = Vbase + (size_t)kt * KT * HD;
        for (int c = tid; c < KT * HD / 8; c += 256) {
            int row = c >> 3, seg = c & 7;
            *(uint4*)&ks[row * LDST + seg * 8] =
                *(const uint4*)&Ksrc[(size_t)row * HD + seg * 8];
            // V: load 8 bf16 of row (key=row), scatter transposed vt[d][key]
            union { uint4 u; u16 e[8]; } vv;
            vv.u = *(const uint4*)&Vsrc[(size_t)row * HD + seg * 8];
#pragma unroll
            for (int j = 0; j < 8; ++j)
                vt[(seg * 8 + j) * LDST + row] = vv.e[j];
        }
        __syncthreads();

        float pv[4][4];
#pragma unroll
        for (int t = 0; t < 4; ++t) {
            short8 b0 = *(const short8*)&ks[(16 * t + lp) * LDST + quad * 8];
            short8 b1 = *(const short8*)&ks[(16 * t + lp) * LDST + 32 + quad * 8];
            floatx4 c = {0.f, 0.f, 0.f, 0.f};
            c = __builtin_amdgcn_mfma_f32_16x16x32_bf16(qa0, b0, c, 0, 0, 0);
            c = __builtin_amdgcn_mfma_f32_16x16x32_bf16(qa1, b1, c, 0, 0, 0);
            int jg = kt * KT + 16 * t + lp;
#pragma unroll
            for (int r = 0; r < 4; ++r) {
                float s = c[r] * 0.125f + slope * (float)(jg - (ig + r));
                float p = __expf(s - m[r]) * invl[r];
                pv[t][r] = p;
                arow[(size_t)(ig + r) * SEQ + jg] = p;
            }
        }
        // P -> LDS (bf16, A-layout round trip)
#pragma unroll
        for (int t = 0; t < 4; ++t)
#pragma unroll
            for (int r = 0; r < 4; ++r)
                ps[(wave * 16 + quad * 4 + r) * LDST + 16 * t + lp] =
                    f32_to_bf16(pv[t][r]);
        __syncthreads();

        short8 pa0 = *(const short8*)&ps[(16 * wave + lp) * LDST + quad * 8];
        short8 pa1 = *(const short8*)&ps[(16 * wave + lp) * LDST + 32 + quad * 8];
#pragma unroll
        for (int t = 0; t < 4; ++t) {
            short8 vb0 = *(const short8*)&vt[(16 * t + lp) * LDST + quad * 8];
            short8 vb1 = *(const short8*)&vt[(16 * t + lp) * LDST + 32 + quad * 8];
            o[t] = __builtin_amdgcn_mfma_f32_16x16x32_bf16(pa0, vb0, o[t], 0, 0, 0);
            o[t] = __builtin_amdgcn_mfma_f32_16x16x32_bf16(pa1, vb1, o[t], 0, 0, 0);
        }
    }

    // ---- write ctx (bf16) ----
    const int b = bh >> 4;
#pragma unroll
    for (int t = 0; t < 4; ++t)
#pragma unroll
        for (int r = 0; r < 4; ++r)
            ctx[((size_t)(b * SEQ + ig + r)) * EMB + h * HD + 16 * t + lp] =
                f32_to_bf16(o[t][r]);
}

// ---------------------------------------------------------------------------

extern "C" void kernel_launch(void* const* d_in, const int* in_sizes, int n_in,
                              void* d_out, int out_size, void* d_ws, size_t ws_size,
                              hipStream_t stream) {
    const float* x    = (const float*)d_in[0];
    const float* Wqkv = (const float*)d_in[1];
    const float* bqkv = (const float*)d_in[2];
    const float* Wout = (const float*)d_in[3];
    const float* bout = (const float*)d_in[4];

    float* out  = (float*)d_out;
    float* attn = out + (size_t)BATCH * SEQ * EMB;

    // Workspace layout (all ushort/bf16). Total = 65,011,712 bytes.
    const size_t HE = (size_t)BATCH * NH * SEQ * HD;   // 4,194,304
    const size_t XE = (size_t)BATCH * SEQ * EMB;       // 4,194,304
    const size_t WE = (size_t)EMB * 3 * EMB;           // 3,145,728
    u16* Qh = (u16*)d_ws;
    u16* Kh = Qh + HE;
    u16* Vh = Kh + HE;
    u16* Ch = Vh + HE;        // ctx bf16 [B,S,EMB]
    u16* Xh = Ch + HE;        // x hi    [M,K]
    u16* Xl = Xh + XE;        // x lo
    u16* Wh = Xl + XE;        // Wqkv^T hi [3E,K]
    u16* Wl = Wh + WE;        // Wqkv^T lo
    u16* Oh = Wl + WE;        // Wout^T bf16 [E,K]

    // 0) input precision prep
    split_bf16<<<dim3(4096), dim3(256), 0, stream>>>(x, Xh, Xl, (int)(XE / 4));
    transpose_split_bf16<<<dim3(96, 32), dim3(256), 0, stream>>>(
        Wqkv, Wh, Wl, EMB, 3 * EMB, 1);
    transpose_split_bf16<<<dim3(32, 32), dim3(256), 0, stream>>>(
        Wout, Oh, nullptr, EMB, EMB, 0);

    // 1) qkv projection (split-precision MFMA) -> bf16 head-split Q/K/V
    gemm_qkv_mfma<<<dim3(24, 32), dim3(256), 0, stream>>>(
        Xh, Xl, Wh, Wl, bqkv, Qh, Kh, Vh);

    // 2) MFMA attention (writes attn + bf16 ctx)
    attn_mfma<<<dim3(SEQ / QT, BATCH * NH), dim3(256), 0, stream>>>(
        Qh, Kh, Vh, attn, Ch);

    // 3) out projection (bf16 MFMA, fp32 out)
    gemm_out_mfma<<<dim3(8, 32), dim3(256), 0, stream>>>(Ch, Oh, bout, out);
}

// Round 3
// 389.431 us; speedup vs baseline: 2.8838x; 1.1654x over previous
//
#include <hip/hip_runtime.h>

// Problem constants
#define BATCH 2
#define SEQ   2048
#define EMB   1024
#define NH    16
#define HD    64

typedef __attribute__((ext_vector_type(8))) _Float16 half8;
typedef __attribute__((ext_vector_type(4))) _Float16 half4;
typedef __attribute__((ext_vector_type(4))) float floatx4;

// ---------------------------------------------------------------------------
// Prep 1: fp32 -> fp16 (RNE), vectorized 8 elems/thread
// ---------------------------------------------------------------------------
__global__ __launch_bounds__(256)
void cvt_f16(const float* __restrict__ in, _Float16* __restrict__ out, int n8) {
    int i = blockIdx.x * 256 + threadIdx.x;
    if (i >= n8) return;
    float4 a = ((const float4*)in)[2 * i];
    float4 b = ((const float4*)in)[2 * i + 1];
    half8 h = {(_Float16)a.x, (_Float16)a.y, (_Float16)a.z, (_Float16)a.w,
               (_Float16)b.x, (_Float16)b.y, (_Float16)b.z, (_Float16)b.w};
    ((half8*)out)[i] = h;
}

// ---------------------------------------------------------------------------
// Prep 2: W [K][N] fp32 -> Wt [N][K] fp16. 32x32 LDS tile.
// ---------------------------------------------------------------------------
__global__ __launch_bounds__(256)
void transpose_f16(const float* __restrict__ W, _Float16* __restrict__ o,
                   int K, int N) {
    __shared__ float t[32][33];
    const int n0 = blockIdx.x * 32, k0 = blockIdx.y * 32;
    const int r = threadIdx.x >> 3, c4 = (threadIdx.x & 7) * 4;
    float4 v = *(const float4*)&W[(size_t)(k0 + r) * N + n0 + c4];
    t[r][c4 + 0] = v.x; t[r][c4 + 1] = v.y;
    t[r][c4 + 2] = v.z; t[r][c4 + 3] = v.w;
    __syncthreads();
    half4 hv;
#pragma unroll
    for (int j = 0; j < 4; ++j) hv[j] = (_Float16)t[c4 + j][r];
    *(half4*)&o[(size_t)(n0 + r) * K + k0 + c4] = hv;
}

// ---------------------------------------------------------------------------
// GEMM1 (single fp16 MFMA): qkv = x @ Wqkv + bqkv.
// 128x128 tile, BK=32, 4 waves, 64x64/wave.
// A = x [M][K] fp16; B = Wqkv^T [N][K] fp16 (k-contiguous).
// Epilogue scatters fp16 into head-split Q/K/V [(b*NH+h)*SEQ + s][HD].
// mfma_f32_16x16x32 layouts (m89-verified):
//   A[m=lane&15][k=quad*8+j]  B[k=quad*8+j][n=lane&15]  D: col=lane&15,
//   row=quad*4+reg.
// ---------------------------------------------------------------------------
#define ALD 40   // LDS row stride in fp16 (80 B): 2-way bank alias = free

__global__ __launch_bounds__(256)
void gemm_qkv_mfma(const _Float16* __restrict__ Xh, const _Float16* __restrict__ Wh,
                   const float* __restrict__ bias,
                   _Float16* __restrict__ Qh, _Float16* __restrict__ Kh,
                   _Float16* __restrict__ Vh) {
    const int K = EMB;   // 1024
    __shared__ _Float16 Ah[128 * ALD];
    __shared__ _Float16 Bh[128 * ALD];

    const int tid  = threadIdx.x;
    const int wave = tid >> 6, lane = tid & 63;
    const int quad = lane >> 4, lp = lane & 15;

    // XCD-aware swizzle: 24x32 = 768 blocks, 768 % 8 == 0 (bijective).
    const int linear = blockIdx.y * 24 + blockIdx.x;
    const int swz = (linear & 7) * 96 + (linear >> 3);
    const int bx = swz % 24, by = swz / 24;
    const int row0 = by * 128, col0 = bx * 128;
    const int wm = (wave >> 1) * 64, wn = (wave & 1) * 64;

    const int srow = tid >> 2, sseg = (tid & 3) * 8;   // staging map

    floatx4 acc[4][4];
#pragma unroll
    for (int i = 0; i < 4; ++i)
#pragma unroll
        for (int j = 0; j < 4; ++j) acc[i][j] = (floatx4){0.f, 0.f, 0.f, 0.f};

    for (int k0 = 0; k0 < K; k0 += 32) {
#pragma unroll
        for (int it = 0; it < 2; ++it) {
            int r = srow + it * 64;
            *(uint4*)&Ah[r * ALD + sseg] =
                *(const uint4*)&Xh[(size_t)(row0 + r) * K + k0 + sseg];
            *(uint4*)&Bh[r * ALD + sseg] =
                *(const uint4*)&Wh[(size_t)(col0 + r) * K + k0 + sseg];
        }
        __syncthreads();

        half8 ah[4];
#pragma unroll
        for (int mi = 0; mi < 4; ++mi)
            ah[mi] = *(const half8*)&Ah[(wm + mi * 16 + lp) * ALD + quad * 8];
#pragma unroll
        for (int ni = 0; ni < 4; ++ni) {
            half8 bh = *(const half8*)&Bh[(wn + ni * 16 + lp) * ALD + quad * 8];
#pragma unroll
            for (int mi = 0; mi < 4; ++mi)
                acc[mi][ni] = __builtin_amdgcn_mfma_f32_16x16x32_f16(
                    ah[mi], bh, acc[mi][ni], 0, 0, 0);
        }
        __syncthreads();
    }

    // epilogue: scatter fp16 into head-split Q/K/V
#pragma unroll
    for (int ni = 0; ni < 4; ++ni) {
        const int c = col0 + wn + ni * 16 + lp;    // 0..3071
        const int h = c / 192;
        const int rem = c - h * 192;
        const int which = rem >> 6;                // 0=q 1=k 2=v
        const int d = rem & 63;
        _Float16* __restrict__ P = (which == 0) ? Qh : (which == 1) ? Kh : Vh;
        const float bb = bias[c];
#pragma unroll
        for (int mi = 0; mi < 4; ++mi) {
            floatx4 a = acc[mi][ni];
#pragma unroll
            for (int r = 0; r < 4; ++r) {
                int m = row0 + wm + mi * 16 + quad * 4 + r;   // b*SEQ + s
                int b = m >> 11, s = m & (SEQ - 1);
                P[((size_t)(b * NH + h) * SEQ + s) * HD + d] =
                    (_Float16)(a[r] + bb);
            }
        }
    }
}

// ---------------------------------------------------------------------------
// GEMM3 (fp16 MFMA): out = ctx @ Wout + bout, fp32 out.
// ---------------------------------------------------------------------------
__global__ __launch_bounds__(256)
void gemm_out_mfma(const _Float16* __restrict__ Ch, const _Float16* __restrict__ Oh,
                   const float* __restrict__ bias, float* __restrict__ out) {
    const int K = EMB, N = EMB;
    __shared__ _Float16 Ah[128 * ALD];
    __shared__ _Float16 Bh[128 * ALD];

    const int tid  = threadIdx.x;
    const int wave = tid >> 6, lane = tid & 63;
    const int quad = lane >> 4, lp = lane & 15;

    // XCD swizzle: 8x32 = 256 blocks, 256 % 8 == 0.
    const int linear = blockIdx.y * 8 + blockIdx.x;
    const int swz = (linear & 7) * 32 + (linear >> 3);
    const int bx = swz & 7, by = swz >> 3;
    const int row0 = by * 128, col0 = bx * 128;
    const int wm = (wave >> 1) * 64, wn = (wave & 1) * 64;

    const int srow = tid >> 2, sseg = (tid & 3) * 8;

    floatx4 acc[4][4];
#pragma unroll
    for (int i = 0; i < 4; ++i)
#pragma unroll
        for (int j = 0; j < 4; ++j) acc[i][j] = (floatx4){0.f, 0.f, 0.f, 0.f};

    for (int k0 = 0; k0 < K; k0 += 32) {
#pragma unroll
        for (int it = 0; it < 2; ++it) {
            int r = srow + it * 64;
            *(uint4*)&Ah[r * ALD + sseg] =
                *(const uint4*)&Ch[(size_t)(row0 + r) * K + k0 + sseg];
            *(uint4*)&Bh[r * ALD + sseg] =
                *(const uint4*)&Oh[(size_t)(col0 + r) * K + k0 + sseg];
        }
        __syncthreads();

        half8 ah[4];
#pragma unroll
        for (int mi = 0; mi < 4; ++mi)
            ah[mi] = *(const half8*)&Ah[(wm + mi * 16 + lp) * ALD + quad * 8];
#pragma unroll
        for (int ni = 0; ni < 4; ++ni) {
            half8 bh = *(const half8*)&Bh[(wn + ni * 16 + lp) * ALD + quad * 8];
#pragma unroll
            for (int mi = 0; mi < 4; ++mi)
                acc[mi][ni] = __builtin_amdgcn_mfma_f32_16x16x32_f16(
                    ah[mi], bh, acc[mi][ni], 0, 0, 0);
        }
        __syncthreads();
    }

#pragma unroll
    for (int ni = 0; ni < 4; ++ni) {
        const int c = col0 + wn + ni * 16 + lp;
        const float bb = bias[c];
#pragma unroll
        for (int mi = 0; mi < 4; ++mi) {
            floatx4 a = acc[mi][ni];
#pragma unroll
            for (int r = 0; r < 4; ++r) {
                int m = row0 + wm + mi * 16 + quad * 4 + r;
                out[(size_t)m * N + c] = a[r] + bb;
            }
        }
    }
}

// ---------------------------------------------------------------------------
// MFMA flash-style attention (fp16), two passes.
// Block: 256 thr = 4 waves, 64 query rows of one (b,h); wave w owns rows
// [16w,16w+16). Pass 2: P staged fp16 in LDS, re-read coalesced for the
// attn-matrix store (float4 x4 per thread); V staged transposed with XOR
// bank swizzle (write-conflict-free, reads stay 16B-contiguous).
// ---------------------------------------------------------------------------
#define QT 64
#define KT 64
#define LDST 72   // LDS row stride in fp16: 144 B (16B-aligned, bank-spread)

__global__ __launch_bounds__(256)
void attn_mfma(const _Float16* __restrict__ Qh,
               const _Float16* __restrict__ Kh,
               const _Float16* __restrict__ Vh,
               float* __restrict__ attn,    // [B,H,S,S]
               _Float16* __restrict__ ctx) { // [B,S,EMB] fp16
    __shared__ _Float16 qs[QT * LDST];
    __shared__ _Float16 ks[KT * LDST];
    __shared__ _Float16 vt[HD * LDST];
    __shared__ _Float16 ps[QT * LDST];

    const int tid  = threadIdx.x;
    const int wave = tid >> 6, lane = tid & 63;
    const int quad = lane >> 4, lp = lane & 15;
    const int q0 = blockIdx.x * QT;
    const int bh = blockIdx.y;                 // b*NH + h
    const int h  = bh & (NH - 1);
    const float slope = exp2f(-0.5f * (float)(h + 1));

    const _Float16* Qbase = Qh + ((size_t)bh * SEQ + q0) * HD;
    const _Float16* Kbase = Kh + (size_t)bh * SEQ * HD;
    const _Float16* Vbase = Vh + (size_t)bh * SEQ * HD;

    // ---- stage Q tile (64 x 64 fp16) ----
    for (int c = tid; c < QT * HD / 8; c += 256) {
        int row = c >> 3, seg = c & 7;
        *(uint4*)&qs[row * LDST + seg * 8] =
            *(const uint4*)&Qbase[(size_t)row * HD + seg * 8];
    }
    __syncthreads();

    const half8 qa0 = *(const half8*)&qs[(16 * wave + lp) * LDST + quad * 8];
    const half8 qa1 = *(const half8*)&qs[(16 * wave + lp) * LDST + 32 + quad * 8];

    const int ig = q0 + 16 * wave + quad * 4;   // +r = global query row

    float m[4], l[4];
#pragma unroll
    for (int r = 0; r < 4; ++r) { m[r] = -1e30f; l[r] = 0.f; }

    // ================= pass 1: online max/sum =================
    for (int kt = 0; kt < SEQ / KT; ++kt) {
        __syncthreads();
        const _Float16* Ksrc = Kbase + (size_t)kt * KT * HD;
        for (int c = tid; c < KT * HD / 8; c += 256) {
            int row = c >> 3, seg = c & 7;
            *(uint4*)&ks[row * LDST + seg * 8] =
                *(const uint4*)&Ksrc[(size_t)row * HD + seg * 8];
        }
        __syncthreads();

        float sv[4][4];
        float tmax[4] = {-1e30f, -1e30f, -1e30f, -1e30f};
#pragma unroll
        for (int t = 0; t < 4; ++t) {
            half8 b0 = *(const half8*)&ks[(16 * t + lp) * LDST + quad * 8];
            half8 b1 = *(const half8*)&ks[(16 * t + lp) * LDST + 32 + quad * 8];
            floatx4 c = {0.f, 0.f, 0.f, 0.f};
            c = __builtin_amdgcn_mfma_f32_16x16x32_f16(qa0, b0, c, 0, 0, 0);
            c = __builtin_amdgcn_mfma_f32_16x16x32_f16(qa1, b1, c, 0, 0, 0);
            int jg = kt * KT + 16 * t + lp;
#pragma unroll
            for (int r = 0; r < 4; ++r) {
                float s = c[r] * 0.125f + slope * (float)(jg - (ig + r));
                sv[t][r] = s;
                tmax[r] = fmaxf(tmax[r], s);
            }
        }
#pragma unroll
        for (int r = 0; r < 4; ++r) {
#pragma unroll
            for (int off = 1; off < 16; off <<= 1)
                tmax[r] = fmaxf(tmax[r], __shfl_xor(tmax[r], off));
            float mn = fmaxf(m[r], tmax[r]);
            float alpha = __expf(m[r] - mn);
            float psum = 0.f;
#pragma unroll
            for (int t = 0; t < 4; ++t) psum += __expf(sv[t][r] - mn);
#pragma unroll
            for (int off = 1; off < 16; off <<= 1)
                psum += __shfl_xor(psum, off);
            l[r] = l[r] * alpha + psum;
            m[r] = mn;
        }
    }

    float invl[4];
#pragma unroll
    for (int r = 0; r < 4; ++r) invl[r] = 1.0f / l[r];

    // ================= pass 2: recompute, write attn, PV =================
    floatx4 o[4];
#pragma unroll
    for (int t = 0; t < 4; ++t) o[t] = (floatx4){0.f, 0.f, 0.f, 0.f};

    float* arow = attn + (size_t)bh * SEQ * SEQ;

    for (int kt = 0; kt < SEQ / KT; ++kt) {
        __syncthreads();
        const _Float16* Ksrc = Kbase + (size_t)kt * KT * HD;
        const _Float16* Vsrc = Vbase + (size_t)kt * KT * HD;
        for (int c = tid; c < KT * HD / 8; c += 256) {
            int row = c >> 3, seg = c & 7;
            *(uint4*)&ks[row * LDST + seg * 8] =
                *(const uint4*)&Ksrc[(size_t)row * HD + seg * 8];
            // V: load 8 fp16 of row (key=row), scatter transposed vt[d][key']
            // with key' = key ^ (seg<<3): write-conflict-free XOR swizzle.
            union { uint4 u; _Float16 e[8]; } vv;
            vv.u = *(const uint4*)&Vsrc[(size_t)row * HD + seg * 8];
            int kbase = row ^ (seg << 3);
#pragma unroll
            for (int j = 0; j < 8; ++j)
                vt[(seg * 8 + j) * LDST + kbase] = vv.e[j];
        }
        __syncthreads();

        // QK^T + softmax -> ps (fp16)
#pragma unroll
        for (int t = 0; t < 4; ++t) {
            half8 b0 = *(const half8*)&ks[(16 * t + lp) * LDST + quad * 8];
            half8 b1 = *(const half8*)&ks[(16 * t + lp) * LDST + 32 + quad * 8];
            floatx4 c = {0.f, 0.f, 0.f, 0.f};
            c = __builtin_amdgcn_mfma_f32_16x16x32_f16(qa0, b0, c, 0, 0, 0);
            c = __builtin_amdgcn_mfma_f32_16x16x32_f16(qa1, b1, c, 0, 0, 0);
            int jg = kt * KT + 16 * t + lp;
#pragma unroll
            for (int r = 0; r < 4; ++r) {
                float s = c[r] * 0.125f + slope * (float)(jg - (ig + r));
                float p = __expf(s - m[r]) * invl[r];
                ps[(wave * 16 + quad * 4 + r) * LDST + 16 * t + lp] =
                    (_Float16)p;
            }
        }
        __syncthreads();

        // coalesced attn-matrix store: thread -> 16 contiguous cols of 1 row
        {
            int lr = tid >> 2;               // local row 0..63
            int c0 = (tid & 3) * 16;         // col seg
            half8 p0 = *(const half8*)&ps[lr * LDST + c0];
            half8 p1 = *(const half8*)&ps[lr * LDST + c0 + 8];
            float* dst = &arow[(size_t)(q0 + lr) * SEQ + kt * KT + c0];
            float4 o0 = {(float)p0[0], (float)p0[1], (float)p0[2], (float)p0[3]};
            float4 o1 = {(float)p0[4], (float)p0[5], (float)p0[6], (float)p0[7]};
            float4 o2 = {(float)p1[0], (float)p1[1], (float)p1[2], (float)p1[3]};
            float4 o3 = {(float)p1[4], (float)p1[5], (float)p1[6], (float)p1[7]};
            *(float4*)&dst[0]  = o0; *(float4*)&dst[4]  = o1;
            *(float4*)&dst[8]  = o2; *(float4*)&dst[12] = o3;
        }

        // PV
        half8 pa0 = *(const half8*)&ps[(16 * wave + lp) * LDST + quad * 8];
        half8 pa1 = *(const half8*)&ps[(16 * wave + lp) * LDST + 32 + quad * 8];
#pragma unroll
        for (int t = 0; t < 4; ++t) {
            int g = 2 * t + (lp >> 3);
            half8 vb0 = *(const half8*)&vt[(16 * t + lp) * LDST + ((quad ^ g) << 3)];
            half8 vb1 = *(const half8*)&vt[(16 * t + lp) * LDST + (((quad + 4) ^ g) << 3)];
            o[t] = __builtin_amdgcn_mfma_f32_16x16x32_f16(pa0, vb0, o[t], 0, 0, 0);
            o[t] = __builtin_amdgcn_mfma_f32_16x16x32_f16(pa1, vb1, o[t], 0, 0, 0);
        }
    }

    // ---- write ctx (fp16) ----
    const int b = bh >> 4;
#pragma unroll
    for (int t = 0; t < 4; ++t)
#pragma unroll
        for (int r = 0; r < 4; ++r)
            ctx[((size_t)(b * SEQ + ig + r)) * EMB + h * HD + 16 * t + lp] =
                (_Float16)o[t][r];
}

// ---------------------------------------------------------------------------

extern "C" void kernel_launch(void* const* d_in, const int* in_sizes, int n_in,
                              void* d_out, int out_size, void* d_ws, size_t ws_size,
                              hipStream_t stream) {
    const float* x    = (const float*)d_in[0];
    const float* Wqkv = (const float*)d_in[1];
    const float* bqkv = (const float*)d_in[2];
    const float* Wout = (const float*)d_in[3];
    const float* bout = (const float*)d_in[4];

    float* out  = (float*)d_out;
    float* attn = out + (size_t)BATCH * SEQ * EMB;

    // Workspace layout (fp16). Total = 50,331,648 bytes.
    const size_t HE = (size_t)BATCH * NH * SEQ * HD;   // 4,194,304
    const size_t XE = (size_t)BATCH * SEQ * EMB;       // 4,194,304
    _Float16* Qh = (_Float16*)d_ws;
    _Float16* Kh = Qh + HE;
    _Float16* Vh = Kh + HE;
    _Float16* Ch = Vh + HE;                 // ctx fp16 [B,S,EMB]
    _Float16* Xh = Ch + XE;                 // x fp16 [M,K]
    _Float16* Wh = Xh + XE;                 // Wqkv^T fp16 [3E,K]
    _Float16* Oh = Wh + (size_t)3 * EMB * EMB;  // Wout^T fp16 [E,K]

    // 0) precision prep
    cvt_f16<<<dim3(2048), dim3(256), 0, stream>>>(x, Xh, (int)(XE / 8));
    transpose_f16<<<dim3(96, 32), dim3(256), 0, stream>>>(Wqkv, Wh, EMB, 3 * EMB);
    transpose_f16<<<dim3(32, 32), dim3(256), 0, stream>>>(Wout, Oh, EMB, EMB);

    // 1) qkv projection (fp16 MFMA) -> fp16 head-split Q/K/V
    gemm_qkv_mfma<<<dim3(24, 32), dim3(256), 0, stream>>>(
        Xh, Wh, bqkv, Qh, Kh, Vh);

    // 2) MFMA attention (writes attn fp32 + ctx fp16)
    attn_mfma<<<dim3(SEQ / QT, BATCH * NH), dim3(256), 0, stream>>>(
        Qh, Kh, Vh, attn, Ch);

    // 3) out projection (fp16 MFMA, fp32 out)
    gemm_out_mfma<<<dim3(8, 32), dim3(256), 0, stream>>>(Ch, Oh, bout, out);
}